// Round 1
// baseline (417.781 us; speedup 1.0000x reference)
//
#include <hip/hip_runtime.h>
#include <math.h>

// Problem constants (from reference): S=4, B=8, C=9, H=W=512
constexpr int  Sn = 4;
constexpr int  Bn = 8;
constexpr int  Cn = 9;
constexpr int  HWc = 512 * 512;                 // 2^18 pixels per (s,b,c) plane
constexpr long SSTRIDE = (long)Bn * Cn * HWc;   // element stride between stages

__device__ __forceinline__ float4 f4(float v) { return make_float4(v, v, v, v); }

__global__ __launch_bounds__(256) void weighted_fusion_kernel(
    const float* __restrict__ pred,   // [S,B,C,H,W]
    const float* __restrict__ wmat,   // [S,C]
    const float* __restrict__ bvec,   // [S]
    float* __restrict__ out)          // [B,C,H,W]
{
    int tid = blockIdx.x * 256 + threadIdx.x;
    long p4 = (long)tid * 4;                 // first pixel this thread owns
    int b  = (int)(p4 >> 18);                // / HW
    int hw = (int)(p4 & (HWc - 1));          // % HW

    const float* tbase = pred + (long)b * Cn * HWc + hw;  // stage-0 base for this thread

    // ---- stage 0 (peeled: init online-softmax state) ----
    float4 acc[Cn];
    float4 m, l;
    {
        float4 pr[Cn];
        float4 wm = f4(bvec[0]);
        #pragma unroll
        for (int c = 0; c < Cn; ++c) {
            pr[c] = *reinterpret_cast<const float4*>(tbase + (long)c * HWc);
            float wc = wmat[c];
            wm.x += pr[c].x * wc; wm.y += pr[c].y * wc;
            wm.z += pr[c].z * wc; wm.w += pr[c].w * wc;
        }
        m = wm;
        l = f4(1.0f);
        #pragma unroll
        for (int c = 0; c < Cn; ++c) acc[c] = pr[c];   // weight = exp(0) = 1
    }

    // ---- stages 1..3 (online softmax update) ----
    #pragma unroll
    for (int s = 1; s < Sn; ++s) {
        float4 pr[Cn];
        float4 wm = f4(bvec[s]);
        #pragma unroll
        for (int c = 0; c < Cn; ++c) {
            pr[c] = *reinterpret_cast<const float4*>(tbase + (long)s * SSTRIDE + (long)c * HWc);
            float wc = wmat[s * Cn + c];
            wm.x += pr[c].x * wc; wm.y += pr[c].y * wc;
            wm.z += pr[c].z * wc; wm.w += pr[c].w * wc;
        }
        float4 nm;
        nm.x = fmaxf(m.x, wm.x); nm.y = fmaxf(m.y, wm.y);
        nm.z = fmaxf(m.z, wm.z); nm.w = fmaxf(m.w, wm.w);
        float4 alpha, pw;
        alpha.x = __expf(m.x - nm.x); alpha.y = __expf(m.y - nm.y);
        alpha.z = __expf(m.z - nm.z); alpha.w = __expf(m.w - nm.w);
        pw.x = __expf(wm.x - nm.x); pw.y = __expf(wm.y - nm.y);
        pw.z = __expf(wm.z - nm.z); pw.w = __expf(wm.w - nm.w);
        l.x = l.x * alpha.x + pw.x; l.y = l.y * alpha.y + pw.y;
        l.z = l.z * alpha.z + pw.z; l.w = l.w * alpha.w + pw.w;
        #pragma unroll
        for (int c = 0; c < Cn; ++c) {
            acc[c].x = acc[c].x * alpha.x + pw.x * pr[c].x;
            acc[c].y = acc[c].y * alpha.y + pw.y * pr[c].y;
            acc[c].z = acc[c].z * alpha.z + pw.z * pr[c].z;
            acc[c].w = acc[c].w * alpha.w + pw.w * pr[c].w;
        }
        m = nm;
    }

    // ---- normalize + store ----
    float4 rl;
    rl.x = 1.0f / l.x; rl.y = 1.0f / l.y; rl.z = 1.0f / l.z; rl.w = 1.0f / l.w;
    float* obase = out + (long)b * Cn * HWc + hw;
    #pragma unroll
    for (int c = 0; c < Cn; ++c) {
        float4 o;
        o.x = acc[c].x * rl.x; o.y = acc[c].y * rl.y;
        o.z = acc[c].z * rl.z; o.w = acc[c].w * rl.w;
        *reinterpret_cast<float4*>(obase + (long)c * HWc) = o;
    }
}

extern "C" void kernel_launch(void* const* d_in, const int* in_sizes, int n_in,
                              void* d_out, int out_size, void* d_ws, size_t ws_size,
                              hipStream_t stream) {
    const float* pred = (const float*)d_in[0];   // [S,B,C,H,W] fp32
    const float* w    = (const float*)d_in[1];   // [S,C] fp32
    const float* bias = (const float*)d_in[2];   // [S] fp32
    float* out        = (float*)d_out;           // [B,C,H,W] fp32

    const int total_threads = (Bn * HWc) / 4;    // 524288: one thread per 4 pixels
    const int block = 256;
    const int grid  = total_threads / block;     // 2048
    weighted_fusion_kernel<<<grid, block, 0, stream>>>(pred, w, bias, out);
}

// Round 3
// 395.958 us; speedup vs baseline: 1.0551x; 1.0551x over previous
//
#include <hip/hip_runtime.h>
#include <math.h>

// Problem constants (from reference): S=4, B=8, C=9, H=W=512
constexpr int  Sn = 4;
constexpr int  Bn = 8;
constexpr int  Cn = 9;
constexpr int  HWc = 512 * 512;                 // 2^18 pixels per (s,b,c) plane
constexpr long SSTRIDE = (long)Bn * Cn * HWc;   // element stride between stages

typedef float v4f __attribute__((ext_vector_type(4)));  // clang vector: OK for nontemporal builtins

__global__ __launch_bounds__(256) void weighted_fusion_kernel(
    const float* __restrict__ pred,   // [S,B,C,H,W]
    const float* __restrict__ wmat,   // [S,C]
    const float* __restrict__ bvec,   // [S]
    float* __restrict__ out)          // [B,C,H,W]
{
    int tid = blockIdx.x * 256 + threadIdx.x;
    long p4 = (long)tid * 4;                 // first pixel this thread owns
    int b  = (int)(p4 >> 18);                // / HW
    int hw = (int)(p4 & (HWc - 1));          // % HW

    const float* tbase = pred + (long)b * Cn * HWc + hw;  // stage-0 base for this thread

    // ---- issue ALL 36 loads up front: 36 KB/wave in flight ----
    v4f pr[Sn][Cn];
    #pragma unroll
    for (int s = 0; s < Sn; ++s) {
        #pragma unroll
        for (int c = 0; c < Cn; ++c) {
            const v4f* p = reinterpret_cast<const v4f*>(
                tbase + (long)s * SSTRIDE + (long)c * HWc);
            pr[s][c] = __builtin_nontemporal_load(p);
        }
    }

    // ---- per-stage 1x1 conv: wm[s] = b[s] + sum_c pr[s][c]*w[s][c] ----
    v4f wm[Sn];
    #pragma unroll
    for (int s = 0; s < Sn; ++s) {
        v4f a = bvec[s];                      // splat
        #pragma unroll
        for (int c = 0; c < Cn; ++c) {
            float wc = wmat[s * Cn + c];
            a += pr[s][c] * wc;
        }
        wm[s] = a;
    }

    // ---- plain softmax over the 4 stages ----
    v4f m = wm[0];
    #pragma unroll
    for (int s = 1; s < Sn; ++s) {
        m.x = fmaxf(m.x, wm[s].x); m.y = fmaxf(m.y, wm[s].y);
        m.z = fmaxf(m.z, wm[s].z); m.w = fmaxf(m.w, wm[s].w);
    }
    v4f p[Sn];
    v4f l = 0.0f;
    #pragma unroll
    for (int s = 0; s < Sn; ++s) {
        p[s].x = __expf(wm[s].x - m.x); p[s].y = __expf(wm[s].y - m.y);
        p[s].z = __expf(wm[s].z - m.z); p[s].w = __expf(wm[s].w - m.w);
        l += p[s];
    }
    v4f rl;
    rl.x = 1.0f / l.x; rl.y = 1.0f / l.y; rl.z = 1.0f / l.z; rl.w = 1.0f / l.w;
    #pragma unroll
    for (int s = 0; s < Sn; ++s) p[s] *= rl;

    // ---- weighted sum over stages, store ----
    float* obase = out + (long)b * Cn * HWc + hw;
    #pragma unroll
    for (int c = 0; c < Cn; ++c) {
        v4f o = p[0] * pr[0][c];
        #pragma unroll
        for (int s = 1; s < Sn; ++s) o += p[s] * pr[s][c];
        __builtin_nontemporal_store(o, reinterpret_cast<v4f*>(obase + (long)c * HWc));
    }
}

extern "C" void kernel_launch(void* const* d_in, const int* in_sizes, int n_in,
                              void* d_out, int out_size, void* d_ws, size_t ws_size,
                              hipStream_t stream) {
    const float* pred = (const float*)d_in[0];   // [S,B,C,H,W] fp32
    const float* w    = (const float*)d_in[1];   // [S,C] fp32
    const float* bias = (const float*)d_in[2];   // [S] fp32
    float* out        = (float*)d_out;           // [B,C,H,W] fp32

    const int total_threads = (Bn * HWc) / 4;    // 524288: one thread per 4 pixels
    const int block = 256;
    const int grid  = total_threads / block;     // 2048
    weighted_fusion_kernel<<<grid, block, 0, stream>>>(pred, w, bias, out);
}

// Round 4
// 393.564 us; speedup vs baseline: 1.0615x; 1.0061x over previous
//
#include <hip/hip_runtime.h>
#include <math.h>

// Problem constants (from reference): S=4, B=8, C=9, H=W=512
constexpr int  Sn = 4;
constexpr int  Bn = 8;
constexpr int  Cn = 9;
constexpr int  HWc = 512 * 512;                 // 2^18 pixels per (s,b,c) plane
constexpr long SSTRIDE = (long)Bn * Cn * HWc;   // element stride between stages

typedef float v2f __attribute__((ext_vector_type(2)));

__global__ __launch_bounds__(256) void weighted_fusion_kernel(
    const float* __restrict__ pred,   // [S,B,C,H,W]
    const float* __restrict__ wmat,   // [S,C]
    const float* __restrict__ bvec,   // [S]
    float* __restrict__ out)          // [B,C,H,W]
{
    int tid = blockIdx.x * 256 + threadIdx.x;
    long p2 = (long)tid * 2;                 // first pixel this thread owns
    int b  = (int)(p2 >> 18);                // / HW
    int hw = (int)(p2 & (HWc - 1));          // % HW

    const float* tbase = pred + (long)b * Cn * HWc + hw;  // stage-0 base for this thread

    // ---- issue ALL 36 loads up front (18 KB/wave in flight), 72 VGPRs of data ----
    v2f pr[Sn][Cn];
    #pragma unroll
    for (int s = 0; s < Sn; ++s) {
        #pragma unroll
        for (int c = 0; c < Cn; ++c) {
            const v2f* p = reinterpret_cast<const v2f*>(
                tbase + (long)s * SSTRIDE + (long)c * HWc);
            pr[s][c] = __builtin_nontemporal_load(p);
        }
    }

    // ---- per-stage 1x1 conv: wm[s] = b[s] + sum_c pr[s][c]*w[s][c] ----
    v2f wm[Sn];
    #pragma unroll
    for (int s = 0; s < Sn; ++s) {
        v2f a = bvec[s];                      // splat
        #pragma unroll
        for (int c = 0; c < Cn; ++c) {
            float wc = wmat[s * Cn + c];
            a += pr[s][c] * wc;
        }
        wm[s] = a;
    }

    // ---- plain softmax over the 4 stages ----
    v2f m = wm[0];
    #pragma unroll
    for (int s = 1; s < Sn; ++s) {
        m.x = fmaxf(m.x, wm[s].x);
        m.y = fmaxf(m.y, wm[s].y);
    }
    v2f p[Sn];
    v2f l = 0.0f;
    #pragma unroll
    for (int s = 0; s < Sn; ++s) {
        p[s].x = __expf(wm[s].x - m.x);
        p[s].y = __expf(wm[s].y - m.y);
        l += p[s];
    }
    v2f rl;
    rl.x = 1.0f / l.x;
    rl.y = 1.0f / l.y;
    #pragma unroll
    for (int s = 0; s < Sn; ++s) p[s] *= rl;

    // ---- weighted sum over stages, store ----
    float* obase = out + (long)b * Cn * HWc + hw;
    #pragma unroll
    for (int c = 0; c < Cn; ++c) {
        v2f o = p[0] * pr[0][c];
        #pragma unroll
        for (int s = 1; s < Sn; ++s) o += p[s] * pr[s][c];
        __builtin_nontemporal_store(o, reinterpret_cast<v2f*>(obase + (long)c * HWc));
    }
}

extern "C" void kernel_launch(void* const* d_in, const int* in_sizes, int n_in,
                              void* d_out, int out_size, void* d_ws, size_t ws_size,
                              hipStream_t stream) {
    const float* pred = (const float*)d_in[0];   // [S,B,C,H,W] fp32
    const float* w    = (const float*)d_in[1];   // [S,C] fp32
    const float* bias = (const float*)d_in[2];   // [S] fp32
    float* out        = (float*)d_out;           // [B,C,H,W] fp32

    const int total_threads = (Bn * HWc) / 2;    // 1048576: one thread per 2 pixels
    const int block = 256;
    const int grid  = total_threads / block;     // 4096
    weighted_fusion_kernel<<<grid, block, 0, stream>>>(pred, w, bias, out);
}